// Round 5
// baseline (143.767 us; speedup 1.0000x reference)
//
#include <hip/hip_runtime.h>

// CrumbReconstructor R8: R7 skeleton + packed-fp32 (v_pk_fma_f32) dual-key
// chains. Cuts hot-loop issue ~41% without changing any float op's order.
//
// R7 post-mortem: issue floor 38.8us vs measured 85 -> 55% stall at 2.05
// waves/SIMD (R3: 24% at 6.1). Pipe models: LDS = 49/G*7680cy, VALU floor
// 34us scalar; at G=6 both ~25us. Lever = fewer instructions per row, same
// math. v_pk_fma_f32 (CDNA full-rate packed fp32) runs TWO keys' chains in
// lo/hi halves; each half is the EXACT original IEEE sequence (mul, 7 fma,
// fma(-2,knorm), add rn) -> bit-identical distances, absmax stays 0.
// Row elements broadcast to both halves via VOP3P op_sel (no movs); the
// 2-row step reads both norms as one ds_read_b64 natural pair.
// Per 2 rows (G=6): 60 pk + 36 cmp/sel + 5 lds + ~6 ovh = 107 instr vs 182.
// Projected VALU/SIMD ~23.6us, LDS/CU ~23.6us.

#define LBLK 8          // memblock length
#define NROW 256        // codebook rows
#define BLOCK 64        // 1 wave per block
#define TARGET_BLOCKS 2048  // 8 blocks/CU on 256 CUs

typedef float f32x2 __attribute__((ext_vector_type(2)));

// v_pk_*_f32: lo-half op and hi-half op are independent IEEE f32 ops.
// op_sel picks the source half feeding the LO op, op_sel_hi for the HI op.
// _bl = broadcast src1.lo to both halves; _bh = broadcast src1.hi.
__device__ __forceinline__ f32x2 pk_mul_bl(f32x2 a, f32x2 b) {
    f32x2 d;
    asm("v_pk_mul_f32 %0, %1, %2 op_sel:[0,0] op_sel_hi:[1,0]"
        : "=v"(d) : "v"(a), "v"(b));
    return d;
}
__device__ __forceinline__ f32x2 pk_fma_bl(f32x2 a, f32x2 b, f32x2 c) {
    f32x2 d;
    asm("v_pk_fma_f32 %0, %1, %2, %3 op_sel:[0,0,0] op_sel_hi:[1,0,1]"
        : "=v"(d) : "v"(a), "v"(b), "v"(c));
    return d;
}
__device__ __forceinline__ f32x2 pk_fma_bh(f32x2 a, f32x2 b, f32x2 c) {
    f32x2 d;
    asm("v_pk_fma_f32 %0, %1, %2, %3 op_sel:[0,1,0] op_sel_hi:[1,1,1]"
        : "=v"(d) : "v"(a), "v"(b), "v"(c));
    return d;
}
__device__ __forceinline__ f32x2 pk_fma_pl(f32x2 a, f32x2 b, f32x2 c) {
    f32x2 d;
    asm("v_pk_fma_f32 %0, %1, %2, %3"
        : "=v"(d) : "v"(a), "v"(b), "v"(c));
    return d;
}
__device__ __forceinline__ f32x2 pk_add_bl(f32x2 a, f32x2 b) {
    f32x2 d;
    asm("v_pk_add_f32 %0, %1, %2 op_sel:[0,0] op_sel_hi:[1,0]"
        : "=v"(d) : "v"(a), "v"(b));
    return d;
}
__device__ __forceinline__ f32x2 pk_add_bh(f32x2 a, f32x2 b) {
    f32x2 d;
    asm("v_pk_add_f32 %0, %1, %2 op_sel:[0,1] op_sel_hi:[1,1]"
        : "=v"(d) : "v"(a), "v"(b));
    return d;
}

template<int G>
__device__ __forceinline__ void scan_groups(
    const float* __restrict__ x,
    float* __restrict__ out,
    const float* __restrict__ s_mem,
    const float* __restrict__ s_norm,
    const int* gi,          // G group indices (each = 64 keys)
    int nblocks, int lane)
{
    constexpr int P   = G / 2;       // packed key pairs
    constexpr int ODD = G & 1;       // trailing scalar key

    float k[G][LBLK];
    float knorm[G];
    int   kb[G];
    bool  valid[G];

    #pragma unroll
    for (int t = 0; t < G; ++t) {
        int b0 = gi[t] * 64 + lane;
        valid[t] = (b0 < nblocks);
        kb[t] = valid[t] ? b0 : 0;
        const float4* g = (const float4*)(x + (long)kb[t] * LBLK);
        float4 a = g[0], b = g[1];
        k[t][0] = a.x; k[t][1] = a.y; k[t][2] = a.z; k[t][3] = a.w;
        k[t][4] = b.x; k[t][5] = b.y; k[t][6] = b.z; k[t][7] = b.w;
        float q0 = a.x * a.x, q1 = a.y * a.y, q2 = a.z * a.z, q3 = a.w * a.w;
        float q4 = b.x * b.x, q5 = b.y * b.y, q6 = b.z * b.z, q7 = b.w * b.w;
        knorm[t] = ((q0 + q1) + (q2 + q3)) + ((q4 + q5) + (q6 + q7));
    }

    // pack key pairs: lo half = key 2p, hi half = key 2p+1
    f32x2 kp[P > 0 ? P : 1][LBLK];
    f32x2 kn2[P > 0 ? P : 1];
    #pragma unroll
    for (int p = 0; p < P; ++p) {
        #pragma unroll
        for (int j = 0; j < LBLK; ++j) {
            f32x2 v; v.x = k[2 * p][j]; v.y = k[2 * p + 1][j];
            kp[p][j] = v;
        }
        f32x2 n; n.x = knorm[2 * p]; n.y = knorm[2 * p + 1];
        kn2[p] = n;
    }
    f32x2 m2; m2.x = -2.0f; m2.y = -2.0f;

    float best[G];
    int   bidx[G];
    #pragma unroll
    for (int t = 0; t < G; ++t) { best[t] = 3.4e38f; bidx[t] = 0; }

    const float4* sm4 = (const float4*)s_mem;

    // preload step 0 (rows 0,1); norms as a natural b64 pair
    float4 A0 = sm4[0], B0 = sm4[1];
    float4 A1 = sm4[2], B1 = sm4[3];
    f32x2 rnp = *(const f32x2*)&s_norm[0];

    #pragma unroll 2
    for (int s = 0; s < NROW / 2; ++s) {
        const int sn = (s + 1) & (NROW / 2 - 1);
        float4 nA0 = sm4[sn * 4 + 0], nB0 = sm4[sn * 4 + 1];
        float4 nA1 = sm4[sn * 4 + 2], nB1 = sm4[sn * 4 + 3];
        f32x2 nrn = *(const f32x2*)&s_norm[sn * 2];

        #pragma unroll
        for (int h = 0; h < 2; ++h) {           // h=0: row 2s, h=1: row 2s+1
            const float4 RA = h ? A1 : A0;
            const float4 RB = h ? B1 : B0;
            f32x2 A01; A01.x = RA.x; A01.y = RA.y;
            f32x2 A23; A23.x = RA.z; A23.y = RA.w;
            f32x2 B45; B45.x = RB.x; B45.y = RB.y;
            f32x2 B67; B67.x = RB.z; B67.y = RB.w;
            const int m = s * 2 + h;

            #pragma unroll
            for (int p = 0; p < P; ++p) {
                // both halves run the exact original sequential chain
                f32x2 acc = pk_mul_bl(kp[p][0], A01);
                acc = pk_fma_bh(kp[p][1], A01, acc);
                acc = pk_fma_bl(kp[p][2], A23, acc);
                acc = pk_fma_bh(kp[p][3], A23, acc);
                acc = pk_fma_bl(kp[p][4], B45, acc);
                acc = pk_fma_bh(kp[p][5], B45, acc);
                acc = pk_fma_bl(kp[p][6], B67, acc);
                acc = pk_fma_bh(kp[p][7], B67, acc);
                f32x2 d2 = pk_fma_pl(acc, m2, kn2[p]);   // fma(dot,-2,knorm)
                d2 = h ? pk_add_bh(d2, rnp) : pk_add_bl(d2, rnp);  // + rn
                // strict < : first (lowest) index wins exact ties (= argmin)
                if (d2.x < best[2 * p])     { best[2 * p] = d2.x;     bidx[2 * p] = m; }
                if (d2.y < best[2 * p + 1]) { best[2 * p + 1] = d2.y; bidx[2 * p + 1] = m; }
            }
            if (ODD) {
                const int t = G - 1;
                float dot = k[t][0] * RA.x;
                dot = fmaf(k[t][1], RA.y, dot);
                dot = fmaf(k[t][2], RA.z, dot);
                dot = fmaf(k[t][3], RA.w, dot);
                dot = fmaf(k[t][4], RB.x, dot);
                dot = fmaf(k[t][5], RB.y, dot);
                dot = fmaf(k[t][6], RB.z, dot);
                dot = fmaf(k[t][7], RB.w, dot);
                float rn = h ? rnp.y : rnp.x;
                float d = fmaf(dot, -2.0f, knorm[t]) + rn;
                if (d < best[t]) { best[t] = d; bidx[t] = m; }
            }
        }

        A0 = nA0; B0 = nB0; A1 = nA1; B1 = nB1; rnp = nrn;
    }

    // --- gather winning rows from LDS, store ---
    #pragma unroll
    for (int t = 0; t < G; ++t) {
        if (valid[t]) {
            float4* o = (float4*)(out + (long)kb[t] * LBLK);
            o[0] = sm4[bidx[t] * 2 + 0];
            o[1] = sm4[bidx[t] * 2 + 1];
        }
    }
}

__global__ __launch_bounds__(BLOCK, 2) void crumb_kernel(
    const float* __restrict__ x,
    const float* __restrict__ mem,
    float* __restrict__ out,
    int nblocks, int gbase, int gextra)
{
    __shared__ float s_mem[NROW * LBLK];            // 8 KB, rows contiguous
    __shared__ __align__(8) float s_norm[NROW];     // 1 KB, b64-pair reads

    const int lane = threadIdx.x;

    // --- stage codebook: 4 rows per thread, coalesced ---
    {
        const float4* g = (const float4*)mem;
        #pragma unroll
        for (int c = 0; c < 4; ++c) {
            const int rr = c * 64 + lane;
            float4 a = g[rr * 2 + 0];
            float4 b = g[rr * 2 + 1];
            ((float4*)s_mem)[rr * 2 + 0] = a;
            ((float4*)s_mem)[rr * 2 + 1] = b;
            float q0 = a.x * a.x, q1 = a.y * a.y, q2 = a.z * a.z, q3 = a.w * a.w;
            float q4 = b.x * b.x, q5 = b.y * b.y, q6 = b.z * b.z, q7 = b.w * b.w;
            s_norm[rr] = ((q0 + q1) + (q2 + q3)) + ((q4 + q5) + (q6 + q7));
        }
    }
    __syncthreads();

    // --- balanced group assignment (R7-proven) ---
    // bp bijection on [0,2048): spreads the 256 seven-group waves so each CU
    // (8 consecutive blocks) gets exactly one. Identity for odd grids.
    const int b = blockIdx.x;
    const int bp = (gridDim.x == TARGET_BLOCKS) ? (((b & 7) << 8) | (b >> 3)) : b;
    const int g = gbase + (bp < gextra ? 1 : 0);
    const int stride = gridDim.x;

    if (g == 7) {
        int gi[7];
        #pragma unroll
        for (int j = 0; j < 7; ++j) gi[j] = j * stride + bp;
        scan_groups<7>(x, out, s_mem, s_norm, gi, nblocks, lane);
    } else if (g == 6) {
        int gi[6];
        #pragma unroll
        for (int j = 0; j < 6; ++j) gi[j] = j * stride + bp;
        scan_groups<6>(x, out, s_mem, s_norm, gi, nblocks, lane);
    } else {
        // generic fallback for non-standard shapes: one group at a time
        for (int j = 0; j < g; ++j) {
            int gi1[1] = { j * stride + bp };
            scan_groups<1>(x, out, s_mem, s_norm, gi1, nblocks, lane);
        }
    }
}

extern "C" void kernel_launch(void* const* d_in, const int* in_sizes, int n_in,
                              void* d_out, int out_size, void* d_ws, size_t ws_size,
                              hipStream_t stream) {
    const float* x   = (const float*)d_in[0];
    const float* mem = (const float*)d_in[1];
    float* out = (float*)d_out;

    int n = in_sizes[0];                 // total x elements
    int nblocks = n / LBLK;              // key-blocks (802816 for std shape)
    int ngroups = (nblocks + 63) / 64;   // 64-key groups (12544)

    int grid = (ngroups < TARGET_BLOCKS) ? (ngroups > 0 ? ngroups : 1)
                                         : TARGET_BLOCKS;
    int gbase  = ngroups / grid;         // 6 for std shape
    int gextra = ngroups % grid;         // 256 for std shape

    hipLaunchKernelGGL(crumb_kernel, dim3(grid), dim3(BLOCK), 0, stream,
                       x, mem, out, nblocks, gbase, gextra);
}